// Round 4
// baseline (234.192 us; speedup 1.0000x reference)
//
#include <hip/hip_runtime.h>
#include <hip/hip_cooperative_groups.h>
#include <math.h>

namespace cg = cooperative_groups;

// LDSLoss via histogram inversion:
//   hot loop: per sample, sq = |in-tg|^2, bin = (i0,i1), ds_add_f32(hist[bin], sq)
//             -- fire-and-forget, no read dependencies, no table gather.
//   epilogue: per block, A = sum_b w_b*hist_b, B = sum_{s_b==0} hist_b,
//             m = max_{hist_b>0, s_b>0} 1/s_b  (coalesced smoothed[] reads)
//   answer  = scaling * (A + m*B) / (2N)      -- identical algebra to reference.
// Single cooperative kernel (grid.sync): 1 graph node, no memset, partials in ws.

#define BLOCK 512
#define GRID_BLKS 512   // 2 blocks/CU * 256 CU, all co-resident (40 KB LDS each)

// searchsorted(bins, x, 'right') - 1, clipped to [0, nb-1].
// Uniform guess (error <= 1) + branchless fixup; the two edge reads are
// independent -> no dependent LDS chain.
__device__ __forceinline__ int find_bin(const float* __restrict__ sb, int nb,
                                        float x, float lo, float inv_step) {
    int g = (int)floorf((x - lo) * inv_step);
    g = g < 0 ? 0 : (g > nb - 1 ? nb - 1 : g);
    float e0 = sb[g];
    float e1 = sb[g + 1];
    g += (x >= e1) ? 1 : 0;
    g -= (x < e0) ? 1 : 0;
    return g < 0 ? 0 : (g > nb - 1 ? nb - 1 : g);
}

__device__ __forceinline__ void process_pair(
    float4 in, float4 tg,
    float* __restrict__ hist,
    const float* __restrict__ sb0, const float* __restrict__ sb1, int nb,
    float lo0, float inv0, float lo1, float inv1)
{
    float dA0 = in.x - tg.x, dA1 = in.y - tg.y;
    float sqA = dA0 * dA0 + dA1 * dA1;
    int iA0 = find_bin(sb0, nb, tg.x, lo0, inv0);
    int iA1 = find_bin(sb1, nb, tg.y, lo1, inv1);
    atomicAdd(&hist[iA0 * nb + iA1], sqA);

    float dB0 = in.z - tg.z, dB1 = in.w - tg.w;
    float sqB = dB0 * dB0 + dB1 * dB1;
    int iB0 = find_bin(sb0, nb, tg.z, lo0, inv0);
    int iB1 = find_bin(sb1, nb, tg.w, lo1, inv1);
    atomicAdd(&hist[iB0 * nb + iB1], sqB);
}

__global__ void __launch_bounds__(BLOCK)
lds_loss_coop(const float* __restrict__ input,
              const float* __restrict__ target,
              const float* __restrict__ smoothed,
              const float* __restrict__ bins0,
              const float* __restrict__ bins1,
              const float* __restrict__ scaling,
              int nb, long long n, long long nelem,
              double* __restrict__ partA,
              double* __restrict__ partB,
              float* __restrict__ partM,
              float* __restrict__ out)
{
    extern __shared__ __align__(16) float smem[];
    float* hist = smem;                        // nb*nb
    float* sb0  = smem + nb * nb;              // nb+1
    float* sb1  = sb0 + (nb + 1);              // nb+1

    const int nbnb = nb * nb;
    for (int i = threadIdx.x; i < nbnb; i += BLOCK) hist[i] = 0.0f;
    for (int i = threadIdx.x; i < nb + 1; i += BLOCK) {
        sb0[i] = bins0[i];
        sb1[i] = bins1[i];
    }
    __syncthreads();

    const float lo0 = sb0[0], inv0 = (float)nb / (sb0[nb] - sb0[0]);
    const float lo1 = sb1[0], inv1 = (float)nb / (sb1[nb] - sb1[0]);

    const long long npair = n >> 1;
    const float4* in4 = (const float4*)input;
    const float4* tg4 = (const float4*)target;
    const long long stride = (long long)gridDim.x * BLOCK;

    long long p = (long long)blockIdx.x * BLOCK + threadIdx.x;
    for (; p + 3 * stride < npair; p += 4 * stride) {
        float4 i0 = in4[p];
        float4 i1 = in4[p + stride];
        float4 i2 = in4[p + 2 * stride];
        float4 i3 = in4[p + 3 * stride];
        float4 t0 = tg4[p];
        float4 t1 = tg4[p + stride];
        float4 t2 = tg4[p + 2 * stride];
        float4 t3 = tg4[p + 3 * stride];
        process_pair(i0, t0, hist, sb0, sb1, nb, lo0, inv0, lo1, inv1);
        process_pair(i1, t1, hist, sb0, sb1, nb, lo0, inv0, lo1, inv1);
        process_pair(i2, t2, hist, sb0, sb1, nb, lo0, inv0, lo1, inv1);
        process_pair(i3, t3, hist, sb0, sb1, nb, lo0, inv0, lo1, inv1);
    }
    for (; p < npair; p += stride) {
        process_pair(in4[p], tg4[p], hist, sb0, sb1, nb, lo0, inv0, lo1, inv1);
    }

    // odd-N tail (not hit for N=8M)
    if ((n & 1) && blockIdx.x == 0 && threadIdx.x == 0) {
        long long i = n - 1;
        float t0 = target[2 * i], t1 = target[2 * i + 1];
        float d0 = input[2 * i] - t0, d1 = input[2 * i + 1] - t1;
        float sq = d0 * d0 + d1 * d1;
        int j0 = find_bin(sb0, nb, t0, lo0, inv0);
        int j1 = find_bin(sb1, nb, t1, lo1, inv1);
        atomicAdd(&hist[j0 * nb + j1], sq);
    }
    __syncthreads();   // all ds_adds visible

    // Epilogue: fold histogram against the weight table (coalesced global reads)
    double A = 0.0, B = 0.0;
    float  m = 0.0f;
    for (int b = threadIdx.x; b < nbnb; b += BLOCK) {
        float h = hist[b];
        float s = smoothed[b];
        if (s == 0.0f) {
            B += (double)h;
        } else {
            float w = 1.0f / s;
            A += (double)w * (double)h;
            if (h > 0.0f) m = fmaxf(m, w);
        }
    }

    #pragma unroll
    for (int off = 32; off > 0; off >>= 1) {
        A += __shfl_down(A, off, 64);
        B += __shfl_down(B, off, 64);
        m = fmaxf(m, __shfl_down(m, off, 64));
    }

    __syncthreads();   // done reading hist; reuse smem as reduction scratch
    double* rA = (double*)smem;                // 8 doubles
    double* rB = rA + (BLOCK / 64);            // 8 doubles
    float*  rM = (float*)(rB + (BLOCK / 64));  // 8 floats
    int wave = threadIdx.x >> 6;
    int lane = threadIdx.x & 63;
    if (lane == 0) { rA[wave] = A; rB[wave] = B; rM[wave] = m; }
    __syncthreads();
    if (threadIdx.x == 0) {
        double ta = 0.0, tb = 0.0; float tm = 0.0f;
        #pragma unroll
        for (int w2 = 0; w2 < BLOCK / 64; ++w2) {
            ta += rA[w2]; tb += rB[w2]; tm = fmaxf(tm, rM[w2]);
        }
        partA[blockIdx.x] = ta;
        partB[blockIdx.x] = tb;
        partM[blockIdx.x] = tm;
    }

    cg::this_grid().sync();

    if (blockIdx.x == 0) {
        int t = threadIdx.x;
        double a2 = (t < (int)gridDim.x) ? partA[t] : 0.0;
        double b2 = (t < (int)gridDim.x) ? partB[t] : 0.0;
        float  m2 = (t < (int)gridDim.x) ? partM[t] : 0.0f;
        #pragma unroll
        for (int off = 32; off > 0; off >>= 1) {
            a2 += __shfl_down(a2, off, 64);
            b2 += __shfl_down(b2, off, 64);
            m2 = fmaxf(m2, __shfl_down(m2, off, 64));
        }
        __syncthreads();
        if (lane == 0) { rA[wave] = a2; rB[wave] = b2; rM[wave] = m2; }
        __syncthreads();
        if (t == 0) {
            double ta = 0.0, tb = 0.0; float tm = 0.0f;
            #pragma unroll
            for (int w2 = 0; w2 < BLOCK / 64; ++w2) {
                ta += rA[w2]; tb += rB[w2]; tm = fmaxf(tm, rM[w2]);
            }
            double v = (double)(*scaling) * (ta + (double)tm * tb) / (double)nelem;
            *out = (float)v;
        }
    }
}

extern "C" void kernel_launch(void* const* d_in, const int* in_sizes, int n_in,
                              void* d_out, int out_size, void* d_ws, size_t ws_size,
                              hipStream_t stream) {
    const float* input    = (const float*)d_in[0];
    const float* target   = (const float*)d_in[1];
    const float* smoothed = (const float*)d_in[2];
    const float* bins0    = (const float*)d_in[3];
    const float* bins1    = (const float*)d_in[4];
    const float* scaling  = (const float*)d_in[5];

    long long nelem = in_sizes[0];       // N * 2
    long long n     = nelem / 2;         // samples
    int       nb    = in_sizes[3] - 1;   // bins (edges - 1)

    // partials: fully overwritten before read -> no init needed
    double* partA = (double*)d_ws;                       // [512]
    double* partB = partA + GRID_BLKS;                   // [512]
    float*  partM = (float*)(partB + GRID_BLKS);         // [512]
    float*  out   = (float*)d_out;

    unsigned int shmem =
        (unsigned int)(((size_t)nb * nb + 2 * (nb + 1)) * sizeof(float));

    void* args[] = {
        (void*)&input, (void*)&target, (void*)&smoothed,
        (void*)&bins0, (void*)&bins1, (void*)&scaling,
        (void*)&nb, (void*)&n, (void*)&nelem,
        (void*)&partA, (void*)&partB, (void*)&partM, (void*)&out
    };

    hipLaunchCooperativeKernel((void*)lds_loss_coop,
                               dim3(GRID_BLKS), dim3(BLOCK),
                               args, shmem, stream);
}

// Round 6
// 188.689 us; speedup vs baseline: 1.2412x; 1.2412x over previous
//
#include <hip/hip_runtime.h>
#include <math.h>

// LDSLoss via histogram inversion + register-double-buffered streaming.
//   hot loop: per sample, sq = |in-tg|^2, bin = (i0,i1), ds_add_f32(hist[bin], sq)
//   epilogue: A = sum_b w_b*hist_b, B = sum_{isinf(w_b)} hist_b,
//             m = max_{hist_b>0, w finite} w_b;  out = scaling*(A + m*B)/(2N)
//
// R5 fix: R2-R4 were latency-bound (VGPR=28..32 -> compiler serialized the
// streaming loads; ~1 load in flight/wave; 16 waves/CU). Now:
//   - BLOCK=1024 + 40KB LDS -> 2 blocks/CU = 32 waves/CU (100% occupancy),
//     enforced via __launch_bounds__(1024, 8) (VGPR <= 64).
//   - explicit 2-stage register pipeline: load next 4 float4s, sched_barrier,
//     process current 4 -> counted vmcnt keeps loads in flight (T4 idiom).

#define BLOCK 1024
#define GRID_BLKS 512   // 2 blocks/CU * 256 CU

// searchsorted(bins, x, 'right') - 1, clipped to [0, nb-1].
// Uniform guess (error <= 1, verified R3/R4 absmax=0) + branchless fixup;
// the two edge reads are independent (no dependent LDS chain).
__device__ __forceinline__ int find_bin(const float* __restrict__ sb, int nb,
                                        float x, float lo, float inv_step) {
    int g = (int)floorf((x - lo) * inv_step);
    g = g < 0 ? 0 : (g > nb - 1 ? nb - 1 : g);
    float e0 = sb[g];
    float e1 = sb[g + 1];
    g += (x >= e1) ? 1 : 0;
    g -= (x < e0) ? 1 : 0;
    return g < 0 ? 0 : (g > nb - 1 ? nb - 1 : g);
}

__device__ __forceinline__ void process_pair(
    float4 in, float4 tg,
    float* __restrict__ hist,
    const float* __restrict__ sb0, const float* __restrict__ sb1, int nb,
    float lo0, float inv0, float lo1, float inv1)
{
    float dA0 = in.x - tg.x, dA1 = in.y - tg.y;
    float sqA = dA0 * dA0 + dA1 * dA1;
    int iA0 = find_bin(sb0, nb, tg.x, lo0, inv0);
    int iA1 = find_bin(sb1, nb, tg.y, lo1, inv1);
    atomicAdd(&hist[iA0 * nb + iA1], sqA);      // ds_add_f32, fire-and-forget

    float dB0 = in.z - tg.z, dB1 = in.w - tg.w;
    float sqB = dB0 * dB0 + dB1 * dB1;
    int iB0 = find_bin(sb0, nb, tg.z, lo0, inv0);
    int iB1 = find_bin(sb1, nb, tg.w, lo1, inv1);
    atomicAdd(&hist[iB0 * nb + iB1], sqB);
}

__global__ void __launch_bounds__(BLOCK, 8)   // 8 waves/SIMD -> VGPR<=64, 2 blk/CU
lds_loss_hist(const float* __restrict__ input,
              const float* __restrict__ target,
              const float* __restrict__ smoothed,
              const float* __restrict__ bins0,
              const float* __restrict__ bins1,
              const float* __restrict__ scaling,
              int nb, long long n, long long nelem,
              double* __restrict__ accA,
              double* __restrict__ accB,
              unsigned int* __restrict__ accM,
              unsigned int* __restrict__ done_ctr,
              float* __restrict__ out)
{
    extern __shared__ __align__(16) float smem[];
    float* hist = smem;                        // nb*nb
    float* sb0  = smem + nb * nb;              // nb+1
    float* sb1  = sb0 + (nb + 1);              // nb+1

    const int nbnb = nb * nb;
    for (int i = threadIdx.x; i < nbnb; i += BLOCK) hist[i] = 0.0f;
    for (int i = threadIdx.x; i < nb + 1; i += BLOCK) {
        sb0[i] = bins0[i];
        sb1[i] = bins1[i];
    }
    __syncthreads();

    const float lo0 = sb0[0], inv0 = (float)nb / (sb0[nb] - sb0[0]);
    const float lo1 = sb1[0], inv1 = (float)nb / (sb1[nb] - sb1[0]);

    const long long npair = n >> 1;
    const float4* in4 = (const float4*)input;
    const float4* tg4 = (const float4*)target;
    const long long S = (long long)gridDim.x * BLOCK;   // pair stride
    const long long STEP = 2 * S;                       // 2 pairs per stage

    long long base = (long long)blockIdx.x * BLOCK + threadIdx.x;

    // 2-stage register pipeline, 2 pairs (4 float4, 64 B) per stage
    float4 ai0, ai1, at0, at1;     // stage buffer A
    float4 bi0, bi1, bt0, bt1;     // stage buffer B

    bool haveA = (base + S) < npair;
    if (haveA) {
        ai0 = in4[base]; ai1 = in4[base + S];
        at0 = tg4[base]; at1 = tg4[base + S];
    }
    while (haveA) {
        long long nxtB = base + STEP;
        bool haveB = (nxtB + S) < npair;
        if (haveB) {
            bi0 = in4[nxtB]; bi1 = in4[nxtB + S];
            bt0 = tg4[nxtB]; bt1 = tg4[nxtB + S];
        }
        __builtin_amdgcn_sched_barrier(0);   // loads above stay above
        process_pair(ai0, at0, hist, sb0, sb1, nb, lo0, inv0, lo1, inv1);
        process_pair(ai1, at1, hist, sb0, sb1, nb, lo0, inv0, lo1, inv1);
        if (!haveB) { base = nxtB; haveA = false; break; }

        long long nxtA = nxtB + STEP;
        haveA = (nxtA + S) < npair;
        if (haveA) {
            ai0 = in4[nxtA]; ai1 = in4[nxtA + S];
            at0 = tg4[nxtA]; at1 = tg4[nxtA + S];
        }
        __builtin_amdgcn_sched_barrier(0);
        process_pair(bi0, bt0, hist, sb0, sb1, nb, lo0, inv0, lo1, inv1);
        process_pair(bi1, bt1, hist, sb0, sb1, nb, lo0, inv0, lo1, inv1);
        base = nxtA;
    }
    // remainder pairs (none for N=8M: npair == 8*S exactly)
    for (long long r = base; r < npair; r += S) {
        process_pair(in4[r], tg4[r], hist, sb0, sb1, nb, lo0, inv0, lo1, inv1);
    }

    // odd-N single-sample tail (not hit for N=8M)
    if ((n & 1) && blockIdx.x == 0 && threadIdx.x == 0) {
        long long i = n - 1;
        float t0 = target[2 * i], t1 = target[2 * i + 1];
        float d0 = input[2 * i] - t0, d1 = input[2 * i + 1] - t1;
        float sq = d0 * d0 + d1 * d1;
        int j0 = find_bin(sb0, nb, t0, lo0, inv0);
        int j1 = find_bin(sb1, nb, t1, lo1, inv1);
        atomicAdd(&hist[j0 * nb + j1], sq);
    }
    __syncthreads();   // all ds_adds visible

    // Epilogue: fold histogram against the weight table (coalesced reads).
    // Classify by isinf(1/s) exactly like the reference (catches subnormal s).
    double A = 0.0, B = 0.0;
    float  m = 0.0f;
    for (int b = threadIdx.x; b < nbnb; b += BLOCK) {
        float h = hist[b];
        float s = smoothed[b];
        float w = 1.0f / s;
        if (isinf(w)) {
            B += (double)h;
        } else {
            A += (double)w * (double)h;
            if (h > 0.0f) m = fmaxf(m, w);
        }
    }

    #pragma unroll
    for (int off = 32; off > 0; off >>= 1) {
        A += __shfl_down(A, off, 64);
        B += __shfl_down(B, off, 64);
        m = fmaxf(m, __shfl_down(m, off, 64));
    }

    __shared__ double rA[BLOCK / 64], rB[BLOCK / 64];
    __shared__ float  rM[BLOCK / 64];
    int wave = threadIdx.x >> 6;
    int lane = threadIdx.x & 63;
    if (lane == 0) { rA[wave] = A; rB[wave] = B; rM[wave] = m; }
    __syncthreads();

    if (threadIdx.x == 0) {
        double ta = 0.0, tb = 0.0; float tm = 0.0f;
        #pragma unroll
        for (int w2 = 0; w2 < BLOCK / 64; ++w2) {
            ta += rA[w2]; tb += rB[w2]; tm = fmaxf(tm, rM[w2]);
        }
        atomicAdd(accA, ta);
        atomicAdd(accB, tb);
        atomicMax(accM, __float_as_uint(tm));   // positive floats: uint order == float
        __threadfence();
        unsigned int prev = atomicAdd(done_ctr, 1u);
        if (prev == gridDim.x - 1) {
            // last block: read back through atomic RMWs (coherent point)
            double Af = atomicAdd(accA, 0.0);
            double Bf = atomicAdd(accB, 0.0);
            float  Mf = __uint_as_float(atomicMax(accM, 0u));
            double v = (double)(*scaling) * (Af + (double)Mf * Bf) / (double)nelem;
            *out = (float)v;
        }
    }
}

extern "C" void kernel_launch(void* const* d_in, const int* in_sizes, int n_in,
                              void* d_out, int out_size, void* d_ws, size_t ws_size,
                              hipStream_t stream) {
    const float* input    = (const float*)d_in[0];
    const float* target   = (const float*)d_in[1];
    const float* smoothed = (const float*)d_in[2];
    const float* bins0    = (const float*)d_in[3];
    const float* bins1    = (const float*)d_in[4];
    const float* scaling  = (const float*)d_in[5];

    const long long nelem = in_sizes[0];       // N * 2
    const long long n     = nelem / 2;         // samples
    const int nb          = in_sizes[3] - 1;   // bins (edges - 1)

    double*       accA = (double*)d_ws;                    // @0
    double*       accB = accA + 1;                         // @8
    unsigned int* accM = (unsigned int*)(accB + 1);        // @16
    unsigned int* ctr  = accM + 1;                         // @20

    // d_ws is poisoned to 0xAA before every launch — zero the accumulators.
    hipMemsetAsync(d_ws, 0, 24, stream);

    long long blocks_needed = (n / 2 + BLOCK - 1) / BLOCK;
    int grid = (int)(blocks_needed < GRID_BLKS ? blocks_needed : GRID_BLKS);
    if (grid < 1) grid = 1;
    // shmem: nb*nb hist + 2*(nb+1) edges. nb=99 -> 40,004 B -> 2 blocks/CU.
    size_t shmem = ((size_t)nb * nb + 2 * (nb + 1)) * sizeof(float);

    lds_loss_hist<<<grid, BLOCK, shmem, stream>>>(
        input, target, smoothed, bins0, bins1, scaling,
        nb, n, nelem, accA, accB, accM, ctr, (float*)d_out);
}